// Round 12
// baseline (322.281 us; speedup 1.0000x reference)
//
#include <hip/hip_runtime.h>
#include <hip/hip_bf16.h>
#include <stdint.h>

#define NB 8192
#define NE 210
#define NS 7
#define NEXP 217
#define NI 8
#define H 128
#define BT 256
#define NTILE (NB / BT)          // 32
// blob per expert: [W1t 4K][bias 2K: bH0,bH1,wo,bo][Wh0 32K][Wh1 32K]
#define BLOB_STRIDE 71680
#define BIAS_OFF 4096
#define WH0_OFF 6144
#define WH1_OFF 38912
#define SMEM_BYTES 67584         // 2K bias + 64K Wh -> 2 blocks/CU
#define TANH_A 4.0

// ws layout (bytes)
#define O_BLOB 0u
#define O_COEF 15555584u         // 36B in the blob..P2 gap (blob ends 15,554,560)
#define O_P2   15560000u         // partial2: 7*8192*4
#define O_F    16000000u
#define O_FS   43525120u
#define O_PART 43754496u

typedef __attribute__((ext_vector_type(8))) short bf16x8;
typedef __attribute__((ext_vector_type(4))) float f32x4;
typedef __attribute__((ext_vector_type(16))) float f32x16;
typedef __attribute__((ext_vector_type(2))) int i32x2;

union I4V { int4 i; bf16x8 v; unsigned u[4]; };
union C16 { f32x16 v; f32x4 q[4]; };

__device__ __forceinline__ unsigned short f2bf(float f) {
  unsigned u = __float_as_uint(f);
  u += 0x7fffu + ((u >> 16) & 1u);
  return (unsigned short)(u >> 16);
}
// deg-17 odd polynomial tanh; coefficients in SGPRs (1 SGPR per fma - legal).
// clamp to [-4,4] first: poly diverges outside the fit range.
__device__ __forceinline__ float poly_tanh(float x, const float (&D)[9]) {
  float xc = __builtin_amdgcn_fmed3f(x, -4.0f, 4.0f);
  float u = xc * xc;
  float q = D[8] * u;
  q = __builtin_fmaf(q, 1.0f, D[7]);   // q = D8*u + D7 (two SGPRs split legally)
  q = __builtin_fmaf(q, u, D[6]);
  q = __builtin_fmaf(q, u, D[5]);
  q = __builtin_fmaf(q, u, D[4]);
  q = __builtin_fmaf(q, u, D[3]);
  q = __builtin_fmaf(q, u, D[2]);
  q = __builtin_fmaf(q, u, D[1]);
  q = __builtin_fmaf(q, u, D[0]);
  return q * xc;
}
__device__ __forceinline__ unsigned pk_bf16(float a, float b) {
  unsigned r;
  asm("v_cvt_pk_bf16_f32 %0, %1, %2" : "=v"(r) : "v"(a), "v"(b));
  return r;
}
__device__ __forceinline__ void glds16(const void* g, void* l) {
  __builtin_amdgcn_global_load_lds(
      (const __attribute__((address_space(1))) unsigned int*)g,
      (__attribute__((address_space(3))) unsigned int*)l, 16, 0, 0);
}

// ---- coefficient fit: Chebyshev projection of tanh(A*s), deg 17 odd ------
__global__ void k_fit(float* __restrict__ D) {
  int k = threadIdx.x;   // 64 nodes
  double th = 3.14159265358979323846 * (k + 0.5) / 64.0;
  double s = cos(th);
  double fx = tanh(TANH_A * s);
  double c[9];
  double Tm2 = 1.0, Tm1 = s;     // T0, T1
  c[0] = fx * s;
  for (int n = 2; n <= 17; ++n) {
    double T = 2.0 * s * Tm1 - Tm2;
    Tm2 = Tm1; Tm1 = T;
    if (n & 1) c[(n - 1) >> 1] = fx * T;
  }
  for (int m = 0; m < 9; ++m) {
    double v = c[m];
    for (int off = 32; off; off >>= 1) v += __shfl_xor(v, off, 64);
    c[m] = v * (2.0 / 64.0);
  }
  if (k == 0) {
    double prev[18], cur[18], nxt[18], B[18];
    for (int j = 0; j < 18; ++j) { prev[j] = 0; cur[j] = 0; B[j] = 0; }
    prev[0] = 1.0; cur[1] = 1.0;
    B[1] = c[0];
    for (int n = 2; n <= 17; ++n) {
      for (int j = 0; j < 18; ++j) nxt[j] = 2.0 * (j ? cur[j - 1] : 0.0) - prev[j];
      if (n & 1) { int m = (n - 1) >> 1; for (int j = 0; j < 18; ++j) B[j] += c[m] * nxt[j]; }
      for (int j = 0; j < 18; ++j) { prev[j] = cur[j]; cur[j] = nxt[j]; }
    }
    double ap = TANH_A;
    for (int j = 0; j < 9; ++j) {
      D[j] = (float)(B[2 * j + 1] / ap);
      ap *= TANH_A * TANH_A;
    }
  }
}

// ---- inter-layer transition (verified R5 permlane mapping) ---------------
__device__ __forceinline__ void transition(const f32x16 (&acc)[4], bf16x8 (&bn)[8],
                                           const float (&D)[9]) {
#pragma unroll
  for (int kk = 0; kk < 8; ++kk) {
    const int ms = kk >> 1, ko = (kk & 1) * 8;
    unsigned P0 = pk_bf16(poly_tanh(acc[ms][ko + 0], D), poly_tanh(acc[ms][ko + 1], D));
    unsigned P1 = pk_bf16(poly_tanh(acc[ms][ko + 2], D), poly_tanh(acc[ms][ko + 3], D));
    unsigned P2 = pk_bf16(poly_tanh(acc[ms][ko + 4], D), poly_tanh(acc[ms][ko + 5], D));
    unsigned P3 = pk_bf16(poly_tanh(acc[ms][ko + 6], D), poly_tanh(acc[ms][ko + 7], D));
    i32x2 s0 = __builtin_amdgcn_permlane32_swap((int)P0, (int)P2, false, false);
    i32x2 s1 = __builtin_amdgcn_permlane32_swap((int)P1, (int)P3, false, false);
    I4V r;
    r.u[0] = (unsigned)s0.x;   // w0
    r.u[1] = (unsigned)s1.x;   // w1
    r.u[2] = (unsigned)s0.y;   // w2
    r.u[3] = (unsigned)s1.y;   // w3
    bn[kk] = r.v;
  }
}

// ---- one hidden layer: K=128 as 8 k-slices; bias enters as C of kk=0 ------
__device__ __forceinline__ void hidden_layer(f32x16 (&acc)[4], const bf16x8 (&bn)[8],
                                             const uint8_t* wb, const float* biaL,
                                             int row, int hi, int hi4) {
  {
    int soff0 = (hi ^ (row & 15)) << 4;
#pragma unroll
    for (int mt = 0; mt < 4; ++mt) {
      bf16x8 aF = *(const bf16x8*)(wb + (mt * 32 + row) * 256 + soff0);
      C16 c0;
#pragma unroll
      for (int i = 0; i < 4; ++i)
        c0.q[i] = *(const f32x4*)(biaL + mt * 32 + i * 8 + hi4);
      acc[mt] = __builtin_amdgcn_mfma_f32_32x32x16_bf16(aF, bn[0], c0.v, 0, 0, 0);
    }
  }
#pragma unroll
  for (int kk = 1; kk < 8; ++kk) {
    int soff = ((2 * kk + hi) ^ (row & 15)) << 4;
#pragma unroll
    for (int mt = 0; mt < 4; ++mt) {
      bf16x8 aF = *(const bf16x8*)(wb + (mt * 32 + row) * 256 + soff);
      acc[mt] = __builtin_amdgcn_mfma_f32_32x32x16_bf16(aF, bn[kk], acc[mt], 0, 0, 0);
    }
  }
}

// ---------------- weight pack (R7 verbatim, unscaled) ----------------------
__global__ __launch_bounds__(128) void k_pack(
    const float* __restrict__ W1, const float* __restrict__ Wh,
    const float* __restrict__ W1s, const float* __restrict__ Whs,
    const float* __restrict__ bh, const float* __restrict__ bhs,
    const float* __restrict__ Wo, const float* __restrict__ Wos,
    const float* __restrict__ bo, const float* __restrict__ bos,
    uint8_t* __restrict__ blob) {
  int bid = blockIdx.x;
  int e = bid / 3, sec = bid % 3;
  int n = threadIdx.x;
  uint8_t* be = blob + (size_t)e * BLOB_STRIDE;
  bool big = e < NE;
  int s = e - NE;
  if (sec == 0) {
    union { int4 v[2]; unsigned short u[16]; } row;
    row.v[0] = make_int4(0, 0, 0, 0);
    row.v[1] = make_int4(0, 0, 0, 0);
    if (big) {
      for (int k = 0; k < NI; ++k) row.u[k] = f2bf(W1[((size_t)e * NI + k) * H + n]);
    } else {
      for (int k = 0; k < 2; ++k) row.u[k] = f2bf(W1s[((size_t)s * 2 + k) * H + n]);
    }
    *(int4*)(be + n * 32) = row.v[0];
    *(int4*)(be + n * 32 + 16) = row.v[1];
    float* bsec = (float*)(be + BIAS_OFF);
    bsec[n]       = big ? bh[(size_t)e * H + n]          : bhs[(size_t)s * H + n];
    bsec[128 + n] = big ? bh[((size_t)NE + e) * H + n]   : bhs[((size_t)NS + s) * H + n];
    bsec[256 + n] = big ? Wo[(size_t)e * H + n]          : Wos[(size_t)s * H + n];
    if (n == 0) bsec[384] = big ? bo[e] : bos[s];
  } else {
    int l = sec - 1;
    union { int4 v[16]; unsigned short u[128]; } row;
    if (big) {
      for (int k = 0; k < H; ++k)
        row.u[k] = f2bf(Wh[(((size_t)l * NE + e) * H + k) * H + n]);
    } else {
      for (int k = 0; k < H; ++k)
        row.u[k] = f2bf(Whs[(((size_t)l * NS + s) * H + k) * H + n]);
    }
    int4* dst = (int4*)(be + (l ? WH1_OFF : WH0_OFF) + n * 256);
    for (int c = 0; c < 16; ++c) dst[c] = row.v[c ^ (n & 15)];
  }
}

// ---------------- F build: normalize + gather, bf16 -----------------------
__global__ __launch_bounds__(256) void k_fbuild(
    const float* __restrict__ F_dist, const float* __restrict__ F_cos,
    const float* __restrict__ F_sin,
    const float* __restrict__ Zd, const float* __restrict__ Zc,
    const float* __restrict__ Zs,
    const int* __restrict__ IDX3, const int* __restrict__ IDX5,
    uint16_t* __restrict__ F, uint16_t* __restrict__ Fs) {
  int bid = blockIdx.x;
  int e = bid >> 5, tile = bid & 31;
  int b = tile * 256 + threadIdx.x;
  if (e < NE) {
    float cv = (F_cos[(size_t)b * NE + e] - Zc[e]) / Zc[NE + e];
    float sv = (F_sin[(size_t)b * NE + e] - Zs[e]) / Zs[NE + e];
    union { int4 v; unsigned short u[8]; } o;
    for (int j = 0; j < 6; ++j) {
      int id = IDX3[e * 6 + j];
      float x = (F_dist[(size_t)b * 45 + id] - Zd[id]) / Zd[45 + id];
      o.u[j] = f2bf(x);
    }
    o.u[6] = f2bf(cv);
    o.u[7] = f2bf(sv);
    *(int4*)(F + ((size_t)e * NB + b) * 8) = o.v;
  } else {
    int s = e - NE;
    int id = IDX5[s];
    float cv = (F_cos[(size_t)b * NE + id] - Zc[id]) / Zc[NE + id];
    float sv = (F_sin[(size_t)b * NE + id] - Zs[id]) / Zs[NE + id];
    unsigned o = (unsigned)f2bf(cv) | ((unsigned)f2bf(sv) << 16);
    *(unsigned*)(Fs + ((size_t)s * NB + b) * 2) = o;
  }
}

// ---------------- main: 3-layer MLP, 32x32x16 MFMA, h in registers --------
__global__ __launch_bounds__(512, 4) void k_main(
    const uint8_t* __restrict__ blob, const float* __restrict__ Dco,
    const uint16_t* __restrict__ F, const uint16_t* __restrict__ Fs,
    const float* __restrict__ b1, const float* __restrict__ b1s,
    float* __restrict__ partial) {
  extern __shared__ __attribute__((aligned(16))) uint8_t smem[];
  // smem: [0:2K bias/wo][2048: Wh0 32K][34816: Wh1 32K]

  int bid = blockIdx.x;
  const int TOT = NEXP * NTILE;    // 6944, divisible by 8
  int lb = (bid & 7) * (TOT >> 3) + (bid >> 3);   // XCD-chunked swizzle
  int e = lb >> 5;
  int tile = lb & 31;
  int brow = tile * BT;

  int t = threadIdx.x;
  int w = t >> 6, lane = t & 63;
  int row = lane & 31, hi = lane >> 5;
  int hi4 = hi << 2;

  bool big = e < NE;
  int s = e - NE;
  const uint8_t* be = blob + (size_t)e * BLOB_STRIDE;

  // tanh poly coefficients -> SGPRs (uniform)
  float D[9];
#pragma unroll
  for (int j = 0; j < 9; ++j)
    D[j] = __uint_as_float(__builtin_amdgcn_readfirstlane(__float_as_uint(Dco[j])));

  // ---- early VMEM (issued BEFORE glds: in-order vmcnt => waiting on these
  //      does not drain the staging queue; L1+transition overlap staging) ----
  I4V bfr;
  bfr.i = make_int4(0, 0, 0, 0);
  if (hi == 0) {
    if (big) {
      bfr.i = *(const int4*)(F + ((size_t)e * NB + brow + w * 32 + row) * 8);
    } else {
      bfr.u[0] = *(const unsigned*)(Fs + ((size_t)s * NB + brow + w * 32 + row) * 2);
    }
  }
  const float* bias1 = big ? b1 + (size_t)e * H : b1s + (size_t)s * H;
  I4V aW[4];
  C16 c1[4];
#pragma unroll
  for (int mt = 0; mt < 4; ++mt) {
    aW[mt].i = *(const int4*)(be + (mt * 32 + row) * 32 + hi * 16);
#pragma unroll
    for (int i = 0; i < 4; ++i)
      c1[mt].q[i] = *(const f32x4*)(bias1 + mt * 32 + i * 8 + hi4);
  }
  __builtin_amdgcn_sched_barrier(0);

  // ---- phase A staging: bias(2) + Wh0(32) chunks; phase B: Wh1(32) -------
  for (int c = w; c < 34; c += 8)
    glds16(be + BIAS_OFF + c * 1024 + lane * 16, smem + c * 1024);
  __builtin_amdgcn_sched_barrier(0);
  for (int c = 34 + w; c < 66; c += 8)
    glds16(be + BIAS_OFF + c * 1024 + lane * 16, smem + c * 1024);
  __builtin_amdgcn_sched_barrier(0);

  // ---- layer 1 (K=16, real 8; hi=1 half zero), no LDS: overlaps staging --
  f32x16 acc[4];
#pragma unroll
  for (int mt = 0; mt < 4; ++mt)
    acc[mt] = __builtin_amdgcn_mfma_f32_32x32x16_bf16(aW[mt].v, bfr.v, c1[mt].v, 0, 0, 0);

  bf16x8 bn[8];
  transition(acc, bn, D);

  // A done (the 4 youngest VMEM ops are always the Wh1 glds) -> layer 0 can
  // run while Wh1 is still in flight.
  asm volatile("s_waitcnt vmcnt(4)" ::: "memory");
  __builtin_amdgcn_s_barrier();
  __builtin_amdgcn_sched_barrier(0);

  hidden_layer(acc, bn, smem + 2048, (const float*)smem, row, hi, hi4);
  transition(acc, bn, D);

  asm volatile("s_waitcnt vmcnt(0)" ::: "memory");
  __builtin_amdgcn_s_barrier();
  __builtin_amdgcn_sched_barrier(0);

  hidden_layer(acc, bn, smem + 34816, (const float*)(smem + 512), row, hi, hi4);

  // ---- output layer: out = bo + sum wo[f]*tanh(acc) -----------------------
  {
    const float* woL = (const float*)(smem + 1024);
    float bout = *(const float*)(smem + 1536);
    float sum = 0.f;
#pragma unroll
    for (int mt = 0; mt < 4; ++mt)
#pragma unroll
      for (int i = 0; i < 4; ++i) {
        f32x4 wq = *(const f32x4*)(woL + mt * 32 + i * 8 + hi4);
#pragma unroll
        for (int j = 0; j < 4; ++j)
          sum += poly_tanh(acc[mt][4 * i + j], D) * wq[j];
      }
    sum += __shfl_xor(sum, 32);
    if (hi == 0)
      partial[(size_t)e * NB + brow + w * 32 + row] = sum + bout;
  }
}

// ---------------- two-stage reduce over experts (217 = 7 x 31) ------------
__global__ __launch_bounds__(256) void k_reduce1(const float* __restrict__ partial,
                                                 float* __restrict__ partial2) {
  int g = blockIdx.x >> 5;         // 7 groups of 31 experts
  int b = (blockIdx.x & 31) * 256 + threadIdx.x;
  const float* p = partial + (size_t)g * 31 * NB + b;
  float s = 0.f;
#pragma unroll
  for (int e = 0; e < 31; ++e) s += p[(size_t)e * NB];
  partial2[(size_t)g * NB + b] = s;
}
__global__ __launch_bounds__(256) void k_reduce2(const float* __restrict__ partial2,
                                                 float* __restrict__ out) {
  int b = blockIdx.x * 256 + threadIdx.x;
  float s = 0.f;
#pragma unroll
  for (int g = 0; g < 7; ++g) s += partial2[(size_t)g * NB + b];
  out[b] = s;
}

extern "C" void kernel_launch(void* const* d_in, const int* in_sizes, int n_in,
                              void* d_out, int out_size, void* d_ws, size_t ws_size,
                              hipStream_t stream) {
  const float* F_dist = (const float*)d_in[0];
  const float* F_cos  = (const float*)d_in[1];
  const float* F_sin  = (const float*)d_in[2];
  // d_in[3] F_angle unused by reference
  const float* Zd  = (const float*)d_in[4];
  const float* Zc  = (const float*)d_in[5];
  const float* Zs  = (const float*)d_in[6];
  const int* IDX3  = (const int*)d_in[7];
  const int* IDX5  = (const int*)d_in[8];
  const float* W1  = (const float*)d_in[9];
  const float* b1  = (const float*)d_in[10];
  const float* Wh  = (const float*)d_in[11];
  const float* bh  = (const float*)d_in[12];
  const float* Wo  = (const float*)d_in[13];
  const float* bo  = (const float*)d_in[14];
  const float* W1s = (const float*)d_in[15];
  const float* b1s = (const float*)d_in[16];
  const float* Whs = (const float*)d_in[17];
  const float* bhs = (const float*)d_in[18];
  const float* Wos = (const float*)d_in[19];
  const float* bos = (const float*)d_in[20];

  uint8_t* ws = (uint8_t*)d_ws;
  uint8_t* blob = ws + O_BLOB;
  float* Dco    = (float*)(ws + O_COEF);
  float* partial2 = (float*)(ws + O_P2);
  uint16_t* F   = (uint16_t*)(ws + O_F);
  uint16_t* Fs  = (uint16_t*)(ws + O_FS);
  float* partial = (float*)(ws + O_PART);

  hipFuncSetAttribute(reinterpret_cast<const void*>(k_main),
                      hipFuncAttributeMaxDynamicSharedMemorySize, SMEM_BYTES);

  k_fit<<<1, 64, 0, stream>>>(Dco);
  k_pack<<<NEXP * 3, 128, 0, stream>>>(W1, Wh, W1s, Whs, bh, bhs, Wo, Wos, bo, bos, blob);
  k_fbuild<<<NEXP * 32, 256, 0, stream>>>(F_dist, F_cos, F_sin, Zd, Zc, Zs,
                                          IDX3, IDX5, F, Fs);
  k_main<<<NEXP * NTILE, 512, SMEM_BYTES, stream>>>(blob, Dco, F, Fs, b1, b1s, partial);
  k_reduce1<<<7 * 32, 256, 0, stream>>>(partial, partial2);
  k_reduce2<<<NB / 256, 256, 0, stream>>>(partial2, (float*)d_out);
}

// Round 13
// 318.471 us; speedup vs baseline: 1.0120x; 1.0120x over previous
//
#include <hip/hip_runtime.h>
#include <hip/hip_bf16.h>
#include <stdint.h>

#define NB 8192
#define NE 210
#define NS 7
#define NEXP 217
#define NI 8
#define H 128
#define BT 256
#define NTILE (NB / BT)          // 32
// blob per expert: [W1t 4K][bias 2K: bH0,bH1,wo,bo][Wh0 32K][Wh1 32K]
#define BLOB_STRIDE 71680
#define BIAS_OFF 4096
#define WH0_OFF 6144
#define WH1_OFF 38912
#define SMEM_BYTES 67584         // 2K bias + 64K Wh -> 2 blocks/CU
#define TANH_A 4.0

// ws layout (bytes)
#define O_BLOB 0u
#define O_COEF 15555584u         // 36B in the blob..P2 gap (blob ends 15,554,560)
#define O_P2   15560000u         // partial2: 7*8192*4
#define O_F    16000000u
#define O_FS   43525120u
#define O_PART 43754496u

typedef __attribute__((ext_vector_type(8))) short bf16x8;
typedef __attribute__((ext_vector_type(4))) float f32x4;
typedef __attribute__((ext_vector_type(16))) float f32x16;
typedef __attribute__((ext_vector_type(2))) int i32x2;

union I4V { int4 i; bf16x8 v; unsigned u[4]; };
union C16 { f32x16 v; f32x4 q[4]; };

__device__ __forceinline__ unsigned short f2bf(float f) {
  unsigned u = __float_as_uint(f);
  u += 0x7fffu + ((u >> 16) & 1u);
  return (unsigned short)(u >> 16);
}
// deg-17 odd polynomial tanh; coefficients are NINE NAMED SCALARS (uniform,
// SGPR-resident) -- R12's float[9] array went to scratch (+15MB WRITE_SIZE).
// Each fma reads exactly 1 SGPR (legal). Clamp [-4,4]: poly diverges outside.
__device__ __forceinline__ float poly_tanh(float x,
    float d0, float d1, float d2, float d3, float d4,
    float d5, float d6, float d7, float d8) {
  float xc = __builtin_amdgcn_fmed3f(x, -4.0f, 4.0f);
  float u = xc * xc;
  float q = d8 * u;             // v_mul (SGPR src0)
  q = q + d7;                   // v_add (1 SGPR)
  q = __builtin_fmaf(q, u, d6);
  q = __builtin_fmaf(q, u, d5);
  q = __builtin_fmaf(q, u, d4);
  q = __builtin_fmaf(q, u, d3);
  q = __builtin_fmaf(q, u, d2);
  q = __builtin_fmaf(q, u, d1);
  q = __builtin_fmaf(q, u, d0);
  return q * xc;
}
#define PT(x) poly_tanh((x), d0, d1, d2, d3, d4, d5, d6, d7, d8)

__device__ __forceinline__ unsigned pk_bf16(float a, float b) {
  unsigned r;
  asm("v_cvt_pk_bf16_f32 %0, %1, %2" : "=v"(r) : "v"(a), "v"(b));
  return r;
}
__device__ __forceinline__ void glds16(const void* g, void* l) {
  __builtin_amdgcn_global_load_lds(
      (const __attribute__((address_space(1))) unsigned int*)g,
      (__attribute__((address_space(3))) unsigned int*)l, 16, 0, 0);
}

// ---- coefficient fit: Chebyshev projection of tanh(A*s), deg 17 odd ------
// (verified numerically by R12's pass, absmax 0.1289)
__global__ void k_fit(float* __restrict__ D) {
  int k = threadIdx.x;   // 64 nodes
  double th = 3.14159265358979323846 * (k + 0.5) / 64.0;
  double s = cos(th);
  double fx = tanh(TANH_A * s);
  double c[9];
  double Tm2 = 1.0, Tm1 = s;     // T0, T1
  c[0] = fx * s;
  for (int n = 2; n <= 17; ++n) {
    double T = 2.0 * s * Tm1 - Tm2;
    Tm2 = Tm1; Tm1 = T;
    if (n & 1) c[(n - 1) >> 1] = fx * T;
  }
  for (int m = 0; m < 9; ++m) {
    double v = c[m];
    for (int off = 32; off; off >>= 1) v += __shfl_xor(v, off, 64);
    c[m] = v * (2.0 / 64.0);
  }
  if (k == 0) {
    double prev[18], cur[18], nxt[18], B[18];
    for (int j = 0; j < 18; ++j) { prev[j] = 0; cur[j] = 0; B[j] = 0; }
    prev[0] = 1.0; cur[1] = 1.0;
    B[1] = c[0];
    for (int n = 2; n <= 17; ++n) {
      for (int j = 0; j < 18; ++j) nxt[j] = 2.0 * (j ? cur[j - 1] : 0.0) - prev[j];
      if (n & 1) { int m = (n - 1) >> 1; for (int j = 0; j < 18; ++j) B[j] += c[m] * nxt[j]; }
      for (int j = 0; j < 18; ++j) { prev[j] = cur[j]; cur[j] = nxt[j]; }
    }
    double ap = TANH_A;
    for (int j = 0; j < 9; ++j) {
      D[j] = (float)(B[2 * j + 1] / ap);
      ap *= TANH_A * TANH_A;
    }
  }
}

// ---- inter-layer transition (verified R5 permlane mapping) ---------------
__device__ __forceinline__ void transition(const f32x16 (&acc)[4], bf16x8 (&bn)[8],
    float d0, float d1, float d2, float d3, float d4,
    float d5, float d6, float d7, float d8) {
#pragma unroll
  for (int kk = 0; kk < 8; ++kk) {
    const int ms = kk >> 1, ko = (kk & 1) * 8;
    unsigned P0 = pk_bf16(PT(acc[ms][ko + 0]), PT(acc[ms][ko + 1]));
    unsigned P1 = pk_bf16(PT(acc[ms][ko + 2]), PT(acc[ms][ko + 3]));
    unsigned P2 = pk_bf16(PT(acc[ms][ko + 4]), PT(acc[ms][ko + 5]));
    unsigned P3 = pk_bf16(PT(acc[ms][ko + 6]), PT(acc[ms][ko + 7]));
    i32x2 s0 = __builtin_amdgcn_permlane32_swap((int)P0, (int)P2, false, false);
    i32x2 s1 = __builtin_amdgcn_permlane32_swap((int)P1, (int)P3, false, false);
    I4V r;
    r.u[0] = (unsigned)s0.x;   // w0
    r.u[1] = (unsigned)s1.x;   // w1
    r.u[2] = (unsigned)s0.y;   // w2
    r.u[3] = (unsigned)s1.y;   // w3
    bn[kk] = r.v;
  }
}

// ---- one hidden layer: K=128 as 8 k-slices; bias enters as C of kk=0 ------
__device__ __forceinline__ void hidden_layer(f32x16 (&acc)[4], const bf16x8 (&bn)[8],
                                             const uint8_t* wb, const float* biaL,
                                             int row, int hi, int hi4) {
  __builtin_amdgcn_s_setprio(1);   // favor MFMA-phase waves (2 blocks/CU drift)
  {
    int soff0 = (hi ^ (row & 15)) << 4;
#pragma unroll
    for (int mt = 0; mt < 4; ++mt) {
      bf16x8 aF = *(const bf16x8*)(wb + (mt * 32 + row) * 256 + soff0);
      C16 c0;
#pragma unroll
      for (int i = 0; i < 4; ++i)
        c0.q[i] = *(const f32x4*)(biaL + mt * 32 + i * 8 + hi4);
      acc[mt] = __builtin_amdgcn_mfma_f32_32x32x16_bf16(aF, bn[0], c0.v, 0, 0, 0);
    }
  }
#pragma unroll
  for (int kk = 1; kk < 8; ++kk) {
    int soff = ((2 * kk + hi) ^ (row & 15)) << 4;
#pragma unroll
    for (int mt = 0; mt < 4; ++mt) {
      bf16x8 aF = *(const bf16x8*)(wb + (mt * 32 + row) * 256 + soff);
      acc[mt] = __builtin_amdgcn_mfma_f32_32x32x16_bf16(aF, bn[kk], acc[mt], 0, 0, 0);
    }
  }
  __builtin_amdgcn_s_setprio(0);
}

// ---------------- weight pack (R7 verbatim, unscaled) ----------------------
__global__ __launch_bounds__(128) void k_pack(
    const float* __restrict__ W1, const float* __restrict__ Wh,
    const float* __restrict__ W1s, const float* __restrict__ Whs,
    const float* __restrict__ bh, const float* __restrict__ bhs,
    const float* __restrict__ Wo, const float* __restrict__ Wos,
    const float* __restrict__ bo, const float* __restrict__ bos,
    uint8_t* __restrict__ blob) {
  int bid = blockIdx.x;
  int e = bid / 3, sec = bid % 3;
  int n = threadIdx.x;
  uint8_t* be = blob + (size_t)e * BLOB_STRIDE;
  bool big = e < NE;
  int s = e - NE;
  if (sec == 0) {
    union { int4 v[2]; unsigned short u[16]; } row;
    row.v[0] = make_int4(0, 0, 0, 0);
    row.v[1] = make_int4(0, 0, 0, 0);
    if (big) {
      for (int k = 0; k < NI; ++k) row.u[k] = f2bf(W1[((size_t)e * NI + k) * H + n]);
    } else {
      for (int k = 0; k < 2; ++k) row.u[k] = f2bf(W1s[((size_t)s * 2 + k) * H + n]);
    }
    *(int4*)(be + n * 32) = row.v[0];
    *(int4*)(be + n * 32 + 16) = row.v[1];
    float* bsec = (float*)(be + BIAS_OFF);
    bsec[n]       = big ? bh[(size_t)e * H + n]          : bhs[(size_t)s * H + n];
    bsec[128 + n] = big ? bh[((size_t)NE + e) * H + n]   : bhs[((size_t)NS + s) * H + n];
    bsec[256 + n] = big ? Wo[(size_t)e * H + n]          : Wos[(size_t)s * H + n];
    if (n == 0) bsec[384] = big ? bo[e] : bos[s];
  } else {
    int l = sec - 1;
    union { int4 v[16]; unsigned short u[128]; } row;
    if (big) {
      for (int k = 0; k < H; ++k)
        row.u[k] = f2bf(Wh[(((size_t)l * NE + e) * H + k) * H + n]);
    } else {
      for (int k = 0; k < H; ++k)
        row.u[k] = f2bf(Whs[(((size_t)l * NS + s) * H + k) * H + n]);
    }
    int4* dst = (int4*)(be + (l ? WH1_OFF : WH0_OFF) + n * 256);
    for (int c = 0; c < 16; ++c) dst[c] = row.v[c ^ (n & 15)];
  }
}

// ---------------- F build: normalize + gather, bf16 -----------------------
__global__ __launch_bounds__(256) void k_fbuild(
    const float* __restrict__ F_dist, const float* __restrict__ F_cos,
    const float* __restrict__ F_sin,
    const float* __restrict__ Zd, const float* __restrict__ Zc,
    const float* __restrict__ Zs,
    const int* __restrict__ IDX3, const int* __restrict__ IDX5,
    uint16_t* __restrict__ F, uint16_t* __restrict__ Fs) {
  int bid = blockIdx.x;
  int e = bid >> 5, tile = bid & 31;
  int b = tile * 256 + threadIdx.x;
  if (e < NE) {
    float cv = (F_cos[(size_t)b * NE + e] - Zc[e]) / Zc[NE + e];
    float sv = (F_sin[(size_t)b * NE + e] - Zs[e]) / Zs[NE + e];
    union { int4 v; unsigned short u[8]; } o;
    for (int j = 0; j < 6; ++j) {
      int id = IDX3[e * 6 + j];
      float x = (F_dist[(size_t)b * 45 + id] - Zd[id]) / Zd[45 + id];
      o.u[j] = f2bf(x);
    }
    o.u[6] = f2bf(cv);
    o.u[7] = f2bf(sv);
    *(int4*)(F + ((size_t)e * NB + b) * 8) = o.v;
  } else {
    int s = e - NE;
    int id = IDX5[s];
    float cv = (F_cos[(size_t)b * NE + id] - Zc[id]) / Zc[NE + id];
    float sv = (F_sin[(size_t)b * NE + id] - Zs[id]) / Zs[NE + id];
    unsigned o = (unsigned)f2bf(cv) | ((unsigned)f2bf(sv) << 16);
    *(unsigned*)(Fs + ((size_t)s * NB + b) * 2) = o;
  }
}

// ---------------- main: 3-layer MLP, 32x32x16 MFMA, h in registers --------
__global__ __launch_bounds__(512, 4) void k_main(
    const uint8_t* __restrict__ blob, const float* __restrict__ Dco,
    const uint16_t* __restrict__ F, const uint16_t* __restrict__ Fs,
    const float* __restrict__ b1, const float* __restrict__ b1s,
    float* __restrict__ partial) {
  extern __shared__ __attribute__((aligned(16))) uint8_t smem[];
  // smem: [0:2K bias/wo][2048: Wh0 32K][34816: Wh1 32K]

  int bid = blockIdx.x;
  const int TOT = NEXP * NTILE;    // 6944, divisible by 8
  int lb = (bid & 7) * (TOT >> 3) + (bid >> 3);   // XCD-chunked swizzle
  int e = lb >> 5;
  int tile = lb & 31;
  int brow = tile * BT;

  int t = threadIdx.x;
  int w = t >> 6, lane = t & 63;
  int row = lane & 31, hi = lane >> 5;
  int hi4 = hi << 2;

  bool big = e < NE;
  int s = e - NE;
  const uint8_t* be = blob + (size_t)e * BLOB_STRIDE;

  // tanh poly coefficients -> 9 NAMED SGPR scalars (no array -> no scratch)
  float d0 = __uint_as_float(__builtin_amdgcn_readfirstlane(__float_as_uint(Dco[0])));
  float d1 = __uint_as_float(__builtin_amdgcn_readfirstlane(__float_as_uint(Dco[1])));
  float d2 = __uint_as_float(__builtin_amdgcn_readfirstlane(__float_as_uint(Dco[2])));
  float d3 = __uint_as_float(__builtin_amdgcn_readfirstlane(__float_as_uint(Dco[3])));
  float d4 = __uint_as_float(__builtin_amdgcn_readfirstlane(__float_as_uint(Dco[4])));
  float d5 = __uint_as_float(__builtin_amdgcn_readfirstlane(__float_as_uint(Dco[5])));
  float d6 = __uint_as_float(__builtin_amdgcn_readfirstlane(__float_as_uint(Dco[6])));
  float d7 = __uint_as_float(__builtin_amdgcn_readfirstlane(__float_as_uint(Dco[7])));
  float d8 = __uint_as_float(__builtin_amdgcn_readfirstlane(__float_as_uint(Dco[8])));

  // ---- early VMEM (issued BEFORE glds: in-order vmcnt => waiting on these
  //      does not drain the staging queue; L1+transition overlap staging) ----
  I4V bfr;
  bfr.i = make_int4(0, 0, 0, 0);
  if (hi == 0) {
    if (big) {
      bfr.i = *(const int4*)(F + ((size_t)e * NB + brow + w * 32 + row) * 8);
    } else {
      bfr.u[0] = *(const unsigned*)(Fs + ((size_t)s * NB + brow + w * 32 + row) * 2);
    }
  }
  const float* bias1 = big ? b1 + (size_t)e * H : b1s + (size_t)s * H;
  I4V aW[4];
  C16 c1[4];
#pragma unroll
  for (int mt = 0; mt < 4; ++mt) {
    aW[mt].i = *(const int4*)(be + (mt * 32 + row) * 32 + hi * 16);
#pragma unroll
    for (int i = 0; i < 4; ++i)
      c1[mt].q[i] = *(const f32x4*)(bias1 + mt * 32 + i * 8 + hi4);
  }
  __builtin_amdgcn_sched_barrier(0);

  // ---- phase A staging: bias(2) + Wh0(32) chunks; phase B: Wh1(32) -------
  for (int c = w; c < 34; c += 8)
    glds16(be + BIAS_OFF + c * 1024 + lane * 16, smem + c * 1024);
  __builtin_amdgcn_sched_barrier(0);
  for (int c = 34 + w; c < 66; c += 8)
    glds16(be + BIAS_OFF + c * 1024 + lane * 16, smem + c * 1024);
  __builtin_amdgcn_sched_barrier(0);

  // ---- layer 1 (K=16, real 8; hi=1 half zero), no LDS: overlaps staging --
  f32x16 acc[4];
#pragma unroll
  for (int mt = 0; mt < 4; ++mt)
    acc[mt] = __builtin_amdgcn_mfma_f32_32x32x16_bf16(aW[mt].v, bfr.v, c1[mt].v, 0, 0, 0);

  bf16x8 bn[8];
  transition(acc, bn, d0, d1, d2, d3, d4, d5, d6, d7, d8);

  // A done (the 4 youngest VMEM ops are always the Wh1 glds) -> layer 0 can
  // run while Wh1 is still in flight.
  asm volatile("s_waitcnt vmcnt(4)" ::: "memory");
  __builtin_amdgcn_s_barrier();
  __builtin_amdgcn_sched_barrier(0);

  hidden_layer(acc, bn, smem + 2048, (const float*)smem, row, hi, hi4);
  transition(acc, bn, d0, d1, d2, d3, d4, d5, d6, d7, d8);

  asm volatile("s_waitcnt vmcnt(0)" ::: "memory");
  __builtin_amdgcn_s_barrier();
  __builtin_amdgcn_sched_barrier(0);

  hidden_layer(acc, bn, smem + 34816, (const float*)(smem + 512), row, hi, hi4);

  // ---- output layer: out = bo + sum wo[f]*tanh(acc) -----------------------
  {
    const float* woL = (const float*)(smem + 1024);
    float bout = *(const float*)(smem + 1536);
    float sum = 0.f;
#pragma unroll
    for (int mt = 0; mt < 4; ++mt)
#pragma unroll
      for (int i = 0; i < 4; ++i) {
        f32x4 wq = *(const f32x4*)(woL + mt * 32 + i * 8 + hi4);
#pragma unroll
        for (int j = 0; j < 4; ++j)
          sum += PT(acc[mt][4 * i + j]) * wq[j];
      }
    sum += __shfl_xor(sum, 32);
    if (hi == 0)
      partial[(size_t)e * NB + brow + w * 32 + row] = sum + bout;
  }
}

// ---------------- two-stage reduce over experts (217 = 7 x 31) ------------
__global__ __launch_bounds__(256) void k_reduce1(const float* __restrict__ partial,
                                                 float* __restrict__ partial2) {
  int g = blockIdx.x >> 5;         // 7 groups of 31 experts
  int b = (blockIdx.x & 31) * 256 + threadIdx.x;
  const float* p = partial + (size_t)g * 31 * NB + b;
  float s = 0.f;
#pragma unroll
  for (int e = 0; e < 31; ++e) s += p[(size_t)e * NB];
  partial2[(size_t)g * NB + b] = s;
}
__global__ __launch_bounds__(256) void k_reduce2(const float* __restrict__ partial2,
                                                 float* __restrict__ out) {
  int b = blockIdx.x * 256 + threadIdx.x;
  float s = 0.f;
#pragma unroll
  for (int g = 0; g < 7; ++g) s += partial2[(size_t)g * NB + b];
  out[b] = s;
}

extern "C" void kernel_launch(void* const* d_in, const int* in_sizes, int n_in,
                              void* d_out, int out_size, void* d_ws, size_t ws_size,
                              hipStream_t stream) {
  const float* F_dist = (const float*)d_in[0];
  const float* F_cos  = (const float*)d_in[1];
  const float* F_sin  = (const float*)d_in[2];
  // d_in[3] F_angle unused by reference
  const float* Zd  = (const float*)d_in[4];
  const float* Zc  = (const float*)d_in[5];
  const float* Zs  = (const float*)d_in[6];
  const int* IDX3  = (const int*)d_in[7];
  const int* IDX5  = (const int*)d_in[8];
  const float* W1  = (const float*)d_in[9];
  const float* b1  = (const float*)d_in[10];
  const float* Wh  = (const float*)d_in[11];
  const float* bh  = (const float*)d_in[12];
  const float* Wo  = (const float*)d_in[13];
  const float* bo  = (const float*)d_in[14];
  const float* W1s = (const float*)d_in[15];
  const float* b1s = (const float*)d_in[16];
  const float* Whs = (const float*)d_in[17];
  const float* bhs = (const float*)d_in[18];
  const float* Wos = (const float*)d_in[19];
  const float* bos = (const float*)d_in[20];

  uint8_t* ws = (uint8_t*)d_ws;
  uint8_t* blob = ws + O_BLOB;
  float* Dco    = (float*)(ws + O_COEF);
  float* partial2 = (float*)(ws + O_P2);
  uint16_t* F   = (uint16_t*)(ws + O_F);
  uint16_t* Fs  = (uint16_t*)(ws + O_FS);
  float* partial = (float*)(ws + O_PART);

  hipFuncSetAttribute(reinterpret_cast<const void*>(k_main),
                      hipFuncAttributeMaxDynamicSharedMemorySize, SMEM_BYTES);

  k_fit<<<1, 64, 0, stream>>>(Dco);
  k_pack<<<NEXP * 3, 128, 0, stream>>>(W1, Wh, W1s, Whs, bh, bhs, Wo, Wos, bo, bos, blob);
  k_fbuild<<<NEXP * 32, 256, 0, stream>>>(F_dist, F_cos, F_sin, Zd, Zc, Zs,
                                          IDX3, IDX5, F, Fs);
  k_main<<<NEXP * NTILE, 512, SMEM_BYTES, stream>>>(blob, Dco, F, Fs, b1, b1s, partial);
  k_reduce1<<<7 * 32, 256, 0, stream>>>(partial, partial2);
  k_reduce2<<<NB / 256, 256, 0, stream>>>(partial2, (float*)d_out);
}

// Round 14
// 245.772 us; speedup vs baseline: 1.3113x; 1.2958x over previous
//
#include <hip/hip_runtime.h>
#include <hip/hip_bf16.h>
#include <stdint.h>

#define NB 8192
#define NE 210
#define NS 7
#define NEXP 217
#define NI 8
#define H 128
#define BT 256
#define NTILE (NB / BT)          // 32
// blob per expert: [W1k 4K][bias 2K: bH0k,bH1k,wo,bo][Wh0k 32K][Wh1k 32K]
#define BLOB_STRIDE 71680
#define BIAS_OFF 4096
#define WH0_OFF 6144
#define WH1_OFF 38912
#define SMEM_BYTES 67584         // 2K bias + 64K Wh -> 2 blocks/CU
#define K2 2.8853900817779268f   // 2/ln2 : tanh(x) = 1 - 2/(1+2^(K2 x))

// ws layout (bytes)
#define O_BLOB 0u
#define O_P2   15560000u         // partial2: 7*8192*4
#define O_F    16000000u
#define O_FS   43525120u
#define O_PART 43754496u

typedef __attribute__((ext_vector_type(8))) short bf16x8;
typedef __attribute__((ext_vector_type(4))) float f32x4;
typedef __attribute__((ext_vector_type(16))) float f32x16;
typedef __attribute__((ext_vector_type(2))) int i32x2;

union I4V { int4 i; bf16x8 v; unsigned u[4]; };
union C16 { f32x16 v; f32x4 q[4]; };

__device__ __forceinline__ unsigned short f2bf(float f) {
  unsigned u = __float_as_uint(f);
  u += 0x7fffu + ((u >> 16) & 1u);
  return (unsigned short)(u >> 16);
}
// input already K2-scaled (weights/biases pre-multiplied by K2 at pack):
// tanh(x) = 1 - 2/(1+2^(K2 x)) -> no per-call multiply. Trans ops (exp2, rcp)
// issue on the quarter-rate pipe -- measured cheaper than any full-rate poly.
__device__ __forceinline__ float fast_tanh_s(float xs) {
  float e = __builtin_amdgcn_exp2f(xs);
  return 1.0f - 2.0f * __builtin_amdgcn_rcpf(1.0f + e);
}
__device__ __forceinline__ unsigned pk_bf16(float a, float b) {
  unsigned r;
  asm("v_cvt_pk_bf16_f32 %0, %1, %2" : "=v"(r) : "v"(a), "v"(b));
  return r;
}
__device__ __forceinline__ void glds16(const void* g, void* l) {
  __builtin_amdgcn_global_load_lds(
      (const __attribute__((address_space(1))) unsigned int*)g,
      (__attribute__((address_space(3))) unsigned int*)l, 16, 0, 0);
}

// ---- inter-layer transition (verified R5 permlane mapping) ---------------
__device__ __forceinline__ void transition(const f32x16 (&acc)[4], bf16x8 (&bn)[8]) {
#pragma unroll
  for (int kk = 0; kk < 8; ++kk) {
    const int ms = kk >> 1, ko = (kk & 1) * 8;
    unsigned P0 = pk_bf16(fast_tanh_s(acc[ms][ko + 0]), fast_tanh_s(acc[ms][ko + 1]));
    unsigned P1 = pk_bf16(fast_tanh_s(acc[ms][ko + 2]), fast_tanh_s(acc[ms][ko + 3]));
    unsigned P2 = pk_bf16(fast_tanh_s(acc[ms][ko + 4]), fast_tanh_s(acc[ms][ko + 5]));
    unsigned P3 = pk_bf16(fast_tanh_s(acc[ms][ko + 6]), fast_tanh_s(acc[ms][ko + 7]));
    i32x2 s0 = __builtin_amdgcn_permlane32_swap((int)P0, (int)P2, false, false);
    i32x2 s1 = __builtin_amdgcn_permlane32_swap((int)P1, (int)P3, false, false);
    I4V r;
    r.u[0] = (unsigned)s0.x;   // w0
    r.u[1] = (unsigned)s1.x;   // w1
    r.u[2] = (unsigned)s0.y;   // w2
    r.u[3] = (unsigned)s1.y;   // w3
    bn[kk] = r.v;
  }
}

// ---- one hidden layer: K=128 as 8 k-slices; bias enters as C of kk=0 ------
__device__ __forceinline__ void hidden_layer(f32x16 (&acc)[4], const bf16x8 (&bn)[8],
                                             const uint8_t* wb, const float* biaL,
                                             int row, int hi, int hi4) {
  __builtin_amdgcn_s_setprio(1);   // T5: favor MFMA-phase waves (2 blocks/CU drift)
  {
    int soff0 = (hi ^ (row & 15)) << 4;
#pragma unroll
    for (int mt = 0; mt < 4; ++mt) {
      bf16x8 aF = *(const bf16x8*)(wb + (mt * 32 + row) * 256 + soff0);
      C16 c0;
#pragma unroll
      for (int i = 0; i < 4; ++i)
        c0.q[i] = *(const f32x4*)(biaL + mt * 32 + i * 8 + hi4);
      acc[mt] = __builtin_amdgcn_mfma_f32_32x32x16_bf16(aF, bn[0], c0.v, 0, 0, 0);
    }
  }
#pragma unroll
  for (int kk = 1; kk < 8; ++kk) {
    int soff = ((2 * kk + hi) ^ (row & 15)) << 4;
#pragma unroll
    for (int mt = 0; mt < 4; ++mt) {
      bf16x8 aF = *(const bf16x8*)(wb + (mt * 32 + row) * 256 + soff);
      acc[mt] = __builtin_amdgcn_mfma_f32_32x32x16_bf16(aF, bn[kk], acc[mt], 0, 0, 0);
    }
  }
  __builtin_amdgcn_s_setprio(0);
}

// ---------------- fused prep: weight pack (K2-prescale) + F build ---------
// blocks [0, NEXP*3): pack expert e=bid/3, section bid%3 (first 128 threads)
// blocks [NEXP*3, NEXP*3 + NEXP*32): F build (256 threads)
__global__ __launch_bounds__(256) void k_prep(
    const float* __restrict__ W1, const float* __restrict__ Wh,
    const float* __restrict__ W1s, const float* __restrict__ Whs,
    const float* __restrict__ bh, const float* __restrict__ bhs,
    const float* __restrict__ Wo, const float* __restrict__ Wos,
    const float* __restrict__ bo, const float* __restrict__ bos,
    const float* __restrict__ F_dist, const float* __restrict__ F_cos,
    const float* __restrict__ F_sin,
    const float* __restrict__ Zd, const float* __restrict__ Zc,
    const float* __restrict__ Zs,
    const int* __restrict__ IDX3, const int* __restrict__ IDX5,
    uint8_t* __restrict__ blob, uint16_t* __restrict__ F,
    uint16_t* __restrict__ Fs) {
  int bid = blockIdx.x;
  if (bid < NEXP * 3) {
    int n = threadIdx.x;
    if (n >= 128) return;
    int e = bid / 3, sec = bid % 3;
    uint8_t* be = blob + (size_t)e * BLOB_STRIDE;
    bool big = e < NE;
    int s = e - NE;
    if (sec == 0) {
      // W1k: 128 rows x 32B (K=16, real k 0..7, rest zero), scaled by K2
      union { int4 v[2]; unsigned short u[16]; } row;
      row.v[0] = make_int4(0, 0, 0, 0);
      row.v[1] = make_int4(0, 0, 0, 0);
      if (big) {
        for (int k = 0; k < NI; ++k) row.u[k] = f2bf(K2 * W1[((size_t)e * NI + k) * H + n]);
      } else {
        for (int k = 0; k < 2; ++k) row.u[k] = f2bf(K2 * W1s[((size_t)s * 2 + k) * H + n]);
      }
      *(int4*)(be + n * 32) = row.v[0];
      *(int4*)(be + n * 32 + 16) = row.v[1];
      // bias section: K2*bH0 | K2*bH1 | wo | bo   (wo/bo NOT scaled)
      float* bsec = (float*)(be + BIAS_OFF);
      bsec[n]       = K2 * (big ? bh[(size_t)e * H + n]        : bhs[(size_t)s * H + n]);
      bsec[128 + n] = K2 * (big ? bh[((size_t)NE + e) * H + n] : bhs[((size_t)NS + s) * H + n]);
      bsec[256 + n] = big ? Wo[(size_t)e * H + n] : Wos[(size_t)s * H + n];
      if (n == 0) bsec[384] = big ? bo[e] : bos[s];
    } else {
      int l = sec - 1;
      union { int4 v[16]; unsigned short u[128]; } row;
      if (big) {
        for (int k = 0; k < H; ++k)
          row.u[k] = f2bf(K2 * Wh[(((size_t)l * NE + e) * H + k) * H + n]);
      } else {
        for (int k = 0; k < H; ++k)
          row.u[k] = f2bf(K2 * Whs[(((size_t)l * NS + s) * H + k) * H + n]);
      }
      int4* dst = (int4*)(be + (l ? WH1_OFF : WH0_OFF) + n * 256);
      for (int c = 0; c < 16; ++c) dst[c] = row.v[c ^ (n & 15)];
    }
  } else {
    int b2 = bid - NEXP * 3;
    int e = b2 >> 5, tile = b2 & 31;
    int b = tile * 256 + threadIdx.x;
    if (e < NE) {
      float cv = (F_cos[(size_t)b * NE + e] - Zc[e]) / Zc[NE + e];
      float sv = (F_sin[(size_t)b * NE + e] - Zs[e]) / Zs[NE + e];
      union { int4 v; unsigned short u[8]; } o;
      for (int j = 0; j < 6; ++j) {
        int id = IDX3[e * 6 + j];
        float x = (F_dist[(size_t)b * 45 + id] - Zd[id]) / Zd[45 + id];
        o.u[j] = f2bf(x);
      }
      o.u[6] = f2bf(cv);
      o.u[7] = f2bf(sv);
      *(int4*)(F + ((size_t)e * NB + b) * 8) = o.v;
    } else {
      int s = e - NE;
      int id = IDX5[s];
      float cv = (F_cos[(size_t)b * NE + id] - Zc[id]) / Zc[NE + id];
      float sv = (F_sin[(size_t)b * NE + id] - Zs[id]) / Zs[NE + id];
      unsigned o = (unsigned)f2bf(cv) | ((unsigned)f2bf(sv) << 16);
      *(unsigned*)(Fs + ((size_t)s * NB + b) * 2) = o;
    }
  }
}

// ---------------- main: 3-layer MLP, 32x32x16 MFMA, h in registers --------
__global__ __launch_bounds__(512, 4) void k_main(
    const uint8_t* __restrict__ blob,
    const uint16_t* __restrict__ F, const uint16_t* __restrict__ Fs,
    const float* __restrict__ b1, const float* __restrict__ b1s,
    float* __restrict__ partial) {
  extern __shared__ __attribute__((aligned(16))) uint8_t smem[];
  // smem: [0:2K bias/wo][2048: Wh0 32K][34816: Wh1 32K]

  int bid = blockIdx.x;
  const int TOT = NEXP * NTILE;    // 6944, divisible by 8
  int lb = (bid & 7) * (TOT >> 3) + (bid >> 3);   // XCD-chunked swizzle
  int e = lb >> 5;
  int tile = lb & 31;
  int brow = tile * BT;

  int t = threadIdx.x;
  int w = t >> 6, lane = t & 63;
  int row = lane & 31, hi = lane >> 5;
  int hi4 = hi << 2;

  bool big = e < NE;
  int s = e - NE;
  const uint8_t* be = blob + (size_t)e * BLOB_STRIDE;

  // ---- early VMEM (issued BEFORE glds: in-order vmcnt => waiting on these
  //      does not drain the staging queue; L1+transition overlap staging) ----
  I4V bfr;
  bfr.i = make_int4(0, 0, 0, 0);
  if (hi == 0) {
    if (big) {
      bfr.i = *(const int4*)(F + ((size_t)e * NB + brow + w * 32 + row) * 8);
    } else {
      bfr.u[0] = *(const unsigned*)(Fs + ((size_t)s * NB + brow + w * 32 + row) * 2);
    }
  }
  const float* bias1 = big ? b1 + (size_t)e * H : b1s + (size_t)s * H;
  I4V aW[4];
  C16 c1[4];
#pragma unroll
  for (int mt = 0; mt < 4; ++mt) {
    aW[mt].i = *(const int4*)(be + (mt * 32 + row) * 32 + hi * 16);
#pragma unroll
    for (int i = 0; i < 4; ++i) {
      f32x4 q = *(const f32x4*)(bias1 + mt * 32 + i * 8 + hi4);
      c1[mt].q[i] = q * K2;     // acc1 = K2*(W1 F + b1)
    }
  }
  __builtin_amdgcn_sched_barrier(0);

  // ---- phase A staging: bias(2) + Wh0(32) chunks; phase B: Wh1(32) -------
  for (int c = w; c < 34; c += 8)
    glds16(be + BIAS_OFF + c * 1024 + lane * 16, smem + c * 1024);
  __builtin_amdgcn_sched_barrier(0);
  for (int c = 34 + w; c < 66; c += 8)
    glds16(be + BIAS_OFF + c * 1024 + lane * 16, smem + c * 1024);
  __builtin_amdgcn_sched_barrier(0);

  // ---- layer 1 (K=16, real 8; hi=1 half zero), no LDS: overlaps staging --
  f32x16 acc[4];
#pragma unroll
  for (int mt = 0; mt < 4; ++mt)
    acc[mt] = __builtin_amdgcn_mfma_f32_32x32x16_bf16(aW[mt].v, bfr.v, c1[mt].v, 0, 0, 0);

  bf16x8 bn[8];
  transition(acc, bn);

  // A done (the 4 youngest VMEM ops are always the Wh1 glds) -> layer 0 can
  // run while Wh1 is still in flight.
  asm volatile("s_waitcnt vmcnt(4)" ::: "memory");
  __builtin_amdgcn_s_barrier();
  __builtin_amdgcn_sched_barrier(0);

  hidden_layer(acc, bn, smem + 2048, (const float*)smem, row, hi, hi4);
  transition(acc, bn);

  asm volatile("s_waitcnt vmcnt(0)" ::: "memory");
  __builtin_amdgcn_s_barrier();
  __builtin_amdgcn_sched_barrier(0);

  hidden_layer(acc, bn, smem + 34816, (const float*)(smem + 512), row, hi, hi4);

  // ---- output layer: out = bo + sum wo[f]*tanh (acc already K2-scaled) ----
  {
    const float* woL = (const float*)(smem + 1024);
    float bout = *(const float*)(smem + 1536);
    float sum = 0.f;
#pragma unroll
    for (int mt = 0; mt < 4; ++mt)
#pragma unroll
      for (int i = 0; i < 4; ++i) {
        f32x4 wq = *(const f32x4*)(woL + mt * 32 + i * 8 + hi4);
#pragma unroll
        for (int j = 0; j < 4; ++j)
          sum += fast_tanh_s(acc[mt][4 * i + j]) * wq[j];
      }
    sum += __shfl_xor(sum, 32);
    if (hi == 0)
      partial[(size_t)e * NB + brow + w * 32 + row] = sum + bout;
  }
}

// ---------------- two-stage reduce over experts (217 = 7 x 31) ------------
__global__ __launch_bounds__(256) void k_reduce1(const float* __restrict__ partial,
                                                 float* __restrict__ partial2) {
  int g = blockIdx.x >> 5;         // 7 groups of 31 experts
  int b = (blockIdx.x & 31) * 256 + threadIdx.x;
  const float* p = partial + (size_t)g * 31 * NB + b;
  float s = 0.f;
#pragma unroll
  for (int e = 0; e < 31; ++e) s += p[(size_t)e * NB];
  partial2[(size_t)g * NB + b] = s;
}
__global__ __launch_bounds__(256) void k_reduce2(const float* __restrict__ partial2,
                                                 float* __restrict__ out) {
  int b = blockIdx.x * 256 + threadIdx.x;
  float s = 0.f;
#pragma unroll
  for (int g = 0; g < 7; ++g) s += partial2[(size_t)g * NB + b];
  out[b] = s;
}

extern "C" void kernel_launch(void* const* d_in, const int* in_sizes, int n_in,
                              void* d_out, int out_size, void* d_ws, size_t ws_size,
                              hipStream_t stream) {
  const float* F_dist = (const float*)d_in[0];
  const float* F_cos  = (const float*)d_in[1];
  const float* F_sin  = (const float*)d_in[2];
  // d_in[3] F_angle unused by reference
  const float* Zd  = (const float*)d_in[4];
  const float* Zc  = (const float*)d_in[5];
  const float* Zs  = (const float*)d_in[6];
  const int* IDX3  = (const int*)d_in[7];
  const int* IDX5  = (const int*)d_in[8];
  const float* W1  = (const float*)d_in[9];
  const float* b1  = (const float*)d_in[10];
  const float* Wh  = (const float*)d_in[11];
  const float* bh  = (const float*)d_in[12];
  const float* Wo  = (const float*)d_in[13];
  const float* bo  = (const float*)d_in[14];
  const float* W1s = (const float*)d_in[15];
  const float* b1s = (const float*)d_in[16];
  const float* Whs = (const float*)d_in[17];
  const float* bhs = (const float*)d_in[18];
  const float* Wos = (const float*)d_in[19];
  const float* bos = (const float*)d_in[20];

  uint8_t* ws = (uint8_t*)d_ws;
  uint8_t* blob = ws + O_BLOB;
  float* partial2 = (float*)(ws + O_P2);
  uint16_t* F   = (uint16_t*)(ws + O_F);
  uint16_t* Fs  = (uint16_t*)(ws + O_FS);
  float* partial = (float*)(ws + O_PART);

  hipFuncSetAttribute(reinterpret_cast<const void*>(k_main),
                      hipFuncAttributeMaxDynamicSharedMemorySize, SMEM_BYTES);

  k_prep<<<NEXP * 3 + NEXP * 32, 256, 0, stream>>>(
      W1, Wh, W1s, Whs, bh, bhs, Wo, Wos, bo, bos,
      F_dist, F_cos, F_sin, Zd, Zc, Zs, IDX3, IDX5, blob, F, Fs);
  k_main<<<NEXP * NTILE, 512, SMEM_BYTES, stream>>>(blob, F, Fs, b1, b1s, partial);
  k_reduce1<<<7 * 32, 256, 0, stream>>>(partial, partial2);
  k_reduce2<<<NB / 256, 256, 0, stream>>>(partial2, (float*)d_out);
}

// Round 15
// 228.787 us; speedup vs baseline: 1.4087x; 1.0742x over previous
//
#include <hip/hip_runtime.h>
#include <hip/hip_bf16.h>
#include <stdint.h>

#define NB 8192
#define NE 210
#define NS 7
#define NEXP 217
#define NI 8
#define H 128
#define BT 256
#define NTILE (NB / BT)          // 32
// blob per expert: [W1k 4K][bias 2K: bH0k,bH1k,wo,bo][Wh0k 32K][Wh1k 32K]
#define BLOB_STRIDE 71680
#define BIAS_OFF 4096
#define WH0_OFF 6144
#define WH1_OFF 38912
#define SMEM_BYTES 67584         // 2K bias + 64K Wh -> 2 blocks/CU
#define K2 2.8853900817779268f   // 2/ln2 : tanh(x) = 1 - 2/(1+2^(K2 x))

// ws layout (bytes); blob ends at 217*71680 = 15,554,560
#define O_NORM 15556000u         // norm tables: 930 floats (3720 B)
#define O_P2   15560000u         // partial2: 7*8192*4
#define O_PART 43754496u

// norm table layout (floats): a_d[45] b_d[45] a_c[210] b_c[210] a_s[210] b_s[210]
#define N_AD 0
#define N_BD 45
#define N_AC 90
#define N_BC 300
#define N_AS 510
#define N_BS 720

typedef __attribute__((ext_vector_type(8))) short bf16x8;
typedef __attribute__((ext_vector_type(4))) float f32x4;
typedef __attribute__((ext_vector_type(16))) float f32x16;
typedef __attribute__((ext_vector_type(2))) int i32x2;

union I4V { int4 i; bf16x8 v; unsigned u[4]; };
union C16 { f32x16 v; f32x4 q[4]; };

__device__ __forceinline__ unsigned short f2bf(float f) {
  unsigned u = __float_as_uint(f);
  u += 0x7fffu + ((u >> 16) & 1u);
  return (unsigned short)(u >> 16);
}
// input already K2-scaled (weights/biases pre-multiplied by K2 at pack):
// tanh(x) = 1 - 2/(1+2^(K2 x)) -> no per-call multiply. Trans ops (exp2, rcp)
// issue on the quarter-rate pipe -- measured cheaper than any full-rate poly.
__device__ __forceinline__ float fast_tanh_s(float xs) {
  float e = __builtin_amdgcn_exp2f(xs);
  return 1.0f - 2.0f * __builtin_amdgcn_rcpf(1.0f + e);
}
__device__ __forceinline__ unsigned pk_bf16(float a, float b) {
  unsigned r;
  asm("v_cvt_pk_bf16_f32 %0, %1, %2" : "=v"(r) : "v"(a), "v"(b));
  return r;
}
__device__ __forceinline__ void glds16(const void* g, void* l) {
  __builtin_amdgcn_global_load_lds(
      (const __attribute__((address_space(1))) unsigned int*)g,
      (__attribute__((address_space(3))) unsigned int*)l, 16, 0, 0);
}

// ---- inter-layer transition (verified R5 permlane mapping) ---------------
__device__ __forceinline__ void transition(const f32x16 (&acc)[4], bf16x8 (&bn)[8]) {
#pragma unroll
  for (int kk = 0; kk < 8; ++kk) {
    const int ms = kk >> 1, ko = (kk & 1) * 8;
    unsigned P0 = pk_bf16(fast_tanh_s(acc[ms][ko + 0]), fast_tanh_s(acc[ms][ko + 1]));
    unsigned P1 = pk_bf16(fast_tanh_s(acc[ms][ko + 2]), fast_tanh_s(acc[ms][ko + 3]));
    unsigned P2 = pk_bf16(fast_tanh_s(acc[ms][ko + 4]), fast_tanh_s(acc[ms][ko + 5]));
    unsigned P3 = pk_bf16(fast_tanh_s(acc[ms][ko + 6]), fast_tanh_s(acc[ms][ko + 7]));
    i32x2 s0 = __builtin_amdgcn_permlane32_swap((int)P0, (int)P2, false, false);
    i32x2 s1 = __builtin_amdgcn_permlane32_swap((int)P1, (int)P3, false, false);
    I4V r;
    r.u[0] = (unsigned)s0.x;   // w0
    r.u[1] = (unsigned)s1.x;   // w1
    r.u[2] = (unsigned)s0.y;   // w2
    r.u[3] = (unsigned)s1.y;   // w3
    bn[kk] = r.v;
  }
}

// ---- one hidden layer: K=128 as 8 k-slices; bias enters as C of kk=0 ------
__device__ __forceinline__ void hidden_layer(f32x16 (&acc)[4], const bf16x8 (&bn)[8],
                                             const uint8_t* wb, const float* biaL,
                                             int row, int hi, int hi4) {
  __builtin_amdgcn_s_setprio(1);   // T5: favor MFMA-phase waves (2 blocks/CU drift)
  {
    int soff0 = (hi ^ (row & 15)) << 4;
#pragma unroll
    for (int mt = 0; mt < 4; ++mt) {
      bf16x8 aF = *(const bf16x8*)(wb + (mt * 32 + row) * 256 + soff0);
      C16 c0;
#pragma unroll
      for (int i = 0; i < 4; ++i)
        c0.q[i] = *(const f32x4*)(biaL + mt * 32 + i * 8 + hi4);
      acc[mt] = __builtin_amdgcn_mfma_f32_32x32x16_bf16(aF, bn[0], c0.v, 0, 0, 0);
    }
  }
#pragma unroll
  for (int kk = 1; kk < 8; ++kk) {
    int soff = ((2 * kk + hi) ^ (row & 15)) << 4;
#pragma unroll
    for (int mt = 0; mt < 4; ++mt) {
      bf16x8 aF = *(const bf16x8*)(wb + (mt * 32 + row) * 256 + soff);
      acc[mt] = __builtin_amdgcn_mfma_f32_32x32x16_bf16(aF, bn[kk], acc[mt], 0, 0, 0);
    }
  }
  __builtin_amdgcn_s_setprio(0);
}

// ---------------- prep: weight pack (K2-prescale) + norm tables -----------
// blocks [0, NEXP*3): pack expert e=bid/3, section bid%3 (first 128 threads)
// block NEXP*3: normalization scale/bias tables (a=1/sigma, b=-mu/sigma)
__global__ __launch_bounds__(256) void k_prep(
    const float* __restrict__ W1, const float* __restrict__ Wh,
    const float* __restrict__ W1s, const float* __restrict__ Whs,
    const float* __restrict__ bh, const float* __restrict__ bhs,
    const float* __restrict__ Wo, const float* __restrict__ Wos,
    const float* __restrict__ bo, const float* __restrict__ bos,
    const float* __restrict__ Zd, const float* __restrict__ Zc,
    const float* __restrict__ Zs,
    uint8_t* __restrict__ blob, float* __restrict__ nrm) {
  int bid = blockIdx.x;
  if (bid == NEXP * 3) {
    int t = threadIdx.x;
    if (t < 45) {
      float a = 1.0f / Zd[45 + t];
      nrm[N_AD + t] = a;
      nrm[N_BD + t] = -Zd[t] * a;
    }
    if (t < 210) {
      float ac = 1.0f / Zc[NE + t];
      nrm[N_AC + t] = ac;
      nrm[N_BC + t] = -Zc[t] * ac;
      float as = 1.0f / Zs[NE + t];
      nrm[N_AS + t] = as;
      nrm[N_BS + t] = -Zs[t] * as;
    }
    return;
  }
  int n = threadIdx.x;
  if (n >= 128) return;
  int e = bid / 3, sec = bid % 3;
  uint8_t* be = blob + (size_t)e * BLOB_STRIDE;
  bool big = e < NE;
  int s = e - NE;
  if (sec == 0) {
    // W1k: 128 rows x 32B (K=16, real k 0..7, rest zero), scaled by K2
    union { int4 v[2]; unsigned short u[16]; } row;
    row.v[0] = make_int4(0, 0, 0, 0);
    row.v[1] = make_int4(0, 0, 0, 0);
    if (big) {
      for (int k = 0; k < NI; ++k) row.u[k] = f2bf(K2 * W1[((size_t)e * NI + k) * H + n]);
    } else {
      for (int k = 0; k < 2; ++k) row.u[k] = f2bf(K2 * W1s[((size_t)s * 2 + k) * H + n]);
    }
    *(int4*)(be + n * 32) = row.v[0];
    *(int4*)(be + n * 32 + 16) = row.v[1];
    // bias section: K2*bH0 | K2*bH1 | wo | bo   (wo/bo NOT scaled)
    float* bsec = (float*)(be + BIAS_OFF);
    bsec[n]       = K2 * (big ? bh[(size_t)e * H + n]        : bhs[(size_t)s * H + n]);
    bsec[128 + n] = K2 * (big ? bh[((size_t)NE + e) * H + n] : bhs[((size_t)NS + s) * H + n]);
    bsec[256 + n] = big ? Wo[(size_t)e * H + n] : Wos[(size_t)s * H + n];
    if (n == 0) bsec[384] = big ? bo[e] : bos[s];
  } else {
    int l = sec - 1;
    union { int4 v[16]; unsigned short u[128]; } row;
    if (big) {
      for (int k = 0; k < H; ++k)
        row.u[k] = f2bf(K2 * Wh[(((size_t)l * NE + e) * H + k) * H + n]);
    } else {
      for (int k = 0; k < H; ++k)
        row.u[k] = f2bf(K2 * Whs[(((size_t)l * NS + s) * H + k) * H + n]);
    }
    int4* dst = (int4*)(be + (l ? WH1_OFF : WH0_OFF) + n * 256);
    for (int c = 0; c < 16; ++c) dst[c] = row.v[c ^ (n & 15)];
  }
}

// ---------------- main: 3-layer MLP, 32x32x16 MFMA, h in registers --------
// Layer-1 inputs gathered+normalized in-register (F never materialized).
__global__ __launch_bounds__(512, 4) void k_main(
    const uint8_t* __restrict__ blob, const float* __restrict__ nrm,
    const float* __restrict__ F_dist, const float* __restrict__ F_cos,
    const float* __restrict__ F_sin,
    const int* __restrict__ IDX3, const int* __restrict__ IDX5,
    const float* __restrict__ b1, const float* __restrict__ b1s,
    float* __restrict__ partial) {
  extern __shared__ __attribute__((aligned(16))) uint8_t smem[];
  // smem: [0:2K bias/wo][2048: Wh0 32K][34816: Wh1 32K]

  int bid = blockIdx.x;
  const int TOT = NEXP * NTILE;    // 6944, divisible by 8
  int lb = (bid & 7) * (TOT >> 3) + (bid >> 3);   // XCD-chunked swizzle
  int e = lb >> 5;
  int tile = lb & 31;
  int brow = tile * BT;

  int t = threadIdx.x;
  int w = t >> 6, lane = t & 63;
  int row = lane & 31, hi = lane >> 5;
  int hi4 = hi << 2;

  bool big = e < NE;
  int s = e - NE;
  const uint8_t* be = blob + (size_t)e * BLOB_STRIDE;

  // ---- early VMEM (issued BEFORE glds: in-order vmcnt => waiting on these
  //      does not drain the staging queue; overlaps weight staging) ---------
  // Layer-1 B-frag: gather + normalize in-register (was k_fbuild + F array).
  I4V bfr;
  bfr.i = make_int4(0, 0, 0, 0);
  if (hi == 0) {
    int bb = brow + w * 32 + row;
    if (big) {
      const int* ix = IDX3 + e * 6;
      float g[6];
#pragma unroll
      for (int j = 0; j < 6; ++j) {
        int id = ix[j];
        g[j] = __builtin_fmaf(F_dist[(size_t)bb * 45 + id], nrm[N_AD + id], nrm[N_BD + id]);
      }
      float cv = __builtin_fmaf(F_cos[(size_t)bb * NE + e], nrm[N_AC + e], nrm[N_BC + e]);
      float sv = __builtin_fmaf(F_sin[(size_t)bb * NE + e], nrm[N_AS + e], nrm[N_BS + e]);
      bfr.u[0] = pk_bf16(g[0], g[1]);
      bfr.u[1] = pk_bf16(g[2], g[3]);
      bfr.u[2] = pk_bf16(g[4], g[5]);
      bfr.u[3] = pk_bf16(cv, sv);
    } else {
      int id5 = IDX5[s];
      float cv = __builtin_fmaf(F_cos[(size_t)bb * NE + id5], nrm[N_AC + id5], nrm[N_BC + id5]);
      float sv = __builtin_fmaf(F_sin[(size_t)bb * NE + id5], nrm[N_AS + id5], nrm[N_BS + id5]);
      bfr.u[0] = pk_bf16(cv, sv);
    }
  }
  const float* bias1 = big ? b1 + (size_t)e * H : b1s + (size_t)s * H;
  I4V aW[4];
  C16 c1[4];
#pragma unroll
  for (int mt = 0; mt < 4; ++mt) {
    aW[mt].i = *(const int4*)(be + (mt * 32 + row) * 32 + hi * 16);
#pragma unroll
    for (int i = 0; i < 4; ++i) {
      f32x4 q = *(const f32x4*)(bias1 + mt * 32 + i * 8 + hi4);
      c1[mt].q[i] = q * K2;     // acc1 = K2*(W1 F + b1)
    }
  }
  __builtin_amdgcn_sched_barrier(0);

  // ---- phase A staging: bias(2) + Wh0(32) chunks; phase B: Wh1(32) -------
  for (int c = w; c < 34; c += 8)
    glds16(be + BIAS_OFF + c * 1024 + lane * 16, smem + c * 1024);
  __builtin_amdgcn_sched_barrier(0);
  for (int c = 34 + w; c < 66; c += 8)
    glds16(be + BIAS_OFF + c * 1024 + lane * 16, smem + c * 1024);
  __builtin_amdgcn_sched_barrier(0);

  // ---- layer 1 (K=16, real 8; hi=1 half zero), no LDS: overlaps staging --
  f32x16 acc[4];
#pragma unroll
  for (int mt = 0; mt < 4; ++mt)
    acc[mt] = __builtin_amdgcn_mfma_f32_32x32x16_bf16(aW[mt].v, bfr.v, c1[mt].v, 0, 0, 0);

  bf16x8 bn[8];
  transition(acc, bn);

  // A done (the 4 youngest VMEM ops are always the Wh1 glds) -> layer 0 can
  // run while Wh1 is still in flight.
  asm volatile("s_waitcnt vmcnt(4)" ::: "memory");
  __builtin_amdgcn_s_barrier();
  __builtin_amdgcn_sched_barrier(0);

  hidden_layer(acc, bn, smem + 2048, (const float*)smem, row, hi, hi4);
  transition(acc, bn);

  asm volatile("s_waitcnt vmcnt(0)" ::: "memory");
  __builtin_amdgcn_s_barrier();
  __builtin_amdgcn_sched_barrier(0);

  hidden_layer(acc, bn, smem + 34816, (const float*)(smem + 512), row, hi, hi4);

  // ---- output layer: out = bo + sum wo[f]*tanh (acc already K2-scaled) ----
  {
    const float* woL = (const float*)(smem + 1024);
    float bout = *(const float*)(smem + 1536);
    float sum = 0.f;
#pragma unroll
    for (int mt = 0; mt < 4; ++mt)
#pragma unroll
      for (int i = 0; i < 4; ++i) {
        f32x4 wq = *(const f32x4*)(woL + mt * 32 + i * 8 + hi4);
#pragma unroll
        for (int j = 0; j < 4; ++j)
          sum += fast_tanh_s(acc[mt][4 * i + j]) * wq[j];
      }
    sum += __shfl_xor(sum, 32);
    if (hi == 0)
      partial[(size_t)e * NB + brow + w * 32 + row] = sum + bout;
  }
}

// ---------------- two-stage reduce over experts (217 = 7 x 31) ------------
__global__ __launch_bounds__(256) void k_reduce1(const float* __restrict__ partial,
                                                 float* __restrict__ partial2) {
  int g = blockIdx.x >> 5;         // 7 groups of 31 experts
  int b = (blockIdx.x & 31) * 256 + threadIdx.x;
  const float* p = partial + (size_t)g * 31 * NB + b;
  float s = 0.f;
#pragma unroll
  for (int e = 0; e < 31; ++e) s += p[(size_t)e * NB];
  partial2[(size_t)g * NB + b] = s;
}
__global__ __launch_bounds__(256) void k_reduce2(const float* __restrict__ partial2,
                                                 float* __restrict__ out) {
  int b = blockIdx.x * 256 + threadIdx.x;
  float s = 0.f;
#pragma unroll
  for (int g = 0; g < 7; ++g) s += partial2[(size_t)g * NB + b];
  out[b] = s;
}

extern "C" void kernel_launch(void* const* d_in, const int* in_sizes, int n_in,
                              void* d_out, int out_size, void* d_ws, size_t ws_size,
                              hipStream_t stream) {
  const float* F_dist = (const float*)d_in[0];
  const float* F_cos  = (const float*)d_in[1];
  const float* F_sin  = (const float*)d_in[2];
  // d_in[3] F_angle unused by reference
  const float* Zd  = (const float*)d_in[4];
  const float* Zc  = (const float*)d_in[5];
  const float* Zs  = (const float*)d_in[6];
  const int* IDX3  = (const int*)d_in[7];
  const int* IDX5  = (const int*)d_in[8];
  const float* W1  = (const float*)d_in[9];
  const float* b1  = (const float*)d_in[10];
  const float* Wh  = (const float*)d_in[11];
  const float* bh  = (const float*)d_in[12];
  const float* Wo  = (const float*)d_in[13];
  const float* bo  = (const float*)d_in[14];
  const float* W1s = (const float*)d_in[15];
  const float* b1s = (const float*)d_in[16];
  const float* Whs = (const float*)d_in[17];
  const float* bhs = (const float*)d_in[18];
  const float* Wos = (const float*)d_in[19];
  const float* bos = (const float*)d_in[20];

  uint8_t* ws = (uint8_t*)d_ws;
  uint8_t* blob = ws;
  float* nrm      = (float*)(ws + O_NORM);
  float* partial2 = (float*)(ws + O_P2);
  float* partial  = (float*)(ws + O_PART);

  hipFuncSetAttribute(reinterpret_cast<const void*>(k_main),
                      hipFuncAttributeMaxDynamicSharedMemorySize, SMEM_BYTES);

  k_prep<<<NEXP * 3 + 1, 256, 0, stream>>>(
      W1, Wh, W1s, Whs, bh, bhs, Wo, Wos, bo, bos, Zd, Zc, Zs, blob, nrm);
  k_main<<<NEXP * NTILE, 512, SMEM_BYTES, stream>>>(
      blob, nrm, F_dist, F_cos, F_sin, IDX3, IDX5, b1, b1s, partial);
  k_reduce1<<<7 * 32, 256, 0, stream>>>(partial, partial2);
  k_reduce2<<<NB / 256, 256, 0, stream>>>(partial2, (float*)d_out);
}